// Round 3
// baseline (1229.593 us; speedup 1.0000x reference)
//
#include <hip/hip_runtime.h>
#include <math.h>

typedef __bf16 bf16_t;
typedef float    f32x2 __attribute__((ext_vector_type(2)));
typedef float    f32x4 __attribute__((ext_vector_type(4)));
typedef unsigned u32x2 __attribute__((ext_vector_type(2)));
typedef unsigned u32x4 __attribute__((ext_vector_type(4)));
typedef __bf16   bf16x8 __attribute__((ext_vector_type(8)));

#define WS_MB (size_t)(1u << 20)

// ---------------- f32 -> bf16 convert (4 elems / thread) ----------------
__global__ __launch_bounds__(256) void cvt_kernel(const float* __restrict__ in,
                                                  bf16_t* __restrict__ out, int n4) {
    int i = blockIdx.x * 256 + threadIdx.x;
    if (i >= n4) return;
    f32x4 v = ((const f32x4*)in)[i];
    union { bf16_t b[4]; u32x2 u; } p;
    p.b[0] = (bf16_t)v.x; p.b[1] = (bf16_t)v.y;
    p.b[2] = (bf16_t)v.z; p.b[3] = (bf16_t)v.w;
    ((u32x2*)out)[i] = p.u;
}

// ---------------- RMSNorm: f32 in -> bf16 out (one block per row, C=512) ----------------
__global__ __launch_bounds__(256) void rmsnorm_kernel(const float* __restrict__ x,
                                                      const float* __restrict__ w,
                                                      bf16_t* __restrict__ out) {
    int row = blockIdx.x;
    const float* xr = x + (size_t)row * 512;
    int t = threadIdx.x;
    f32x2 v = *(const f32x2*)(xr + t * 2);
    float ss = v.x * v.x + v.y * v.y;
#pragma unroll
    for (int o = 32; o > 0; o >>= 1) ss += __shfl_down(ss, o);
    __shared__ float red[4];
    if ((t & 63) == 0) red[t >> 6] = ss;
    __syncthreads();
    float tot = (red[0] + red[1]) + (red[2] + red[3]);
    float sc = rsqrtf(tot * (1.0f / 512.0f) + 1e-5f);
    f32x2 wv = *(const f32x2*)(w + t * 2);
    union { bf16_t b[2]; unsigned u; } p;
    p.b[0] = (bf16_t)(v.x * sc * wv.x);
    p.b[1] = (bf16_t)(v.y * sc * wv.y);
    *(unsigned*)(out + (size_t)row * 512 + t * 2) = p.u;
}

__device__ inline float gelu_exact(float v) {
    return 0.5f * v * (1.0f + erff(v * 0.70710678118654752f));
}

// ---------------- bf16 MFMA GEMM: C[n,o] = sum_c A[n,c]*B[o,c] ----------------
// 128x128 tile, BK=32, 4 waves (2x2), 4x4 16x16 frags per wave.
// EPI: 1 = f32 out = acc + aux[idx] (residual add)
//      2 = bf16 out = gelu(acc)
//      3 = f32 out += aux[row*4] * acc   (MoE weighted accumulate; aux pre-offset by expert)
//      4 = bf16 out = acc
template <int EPI>
__global__ __launch_bounds__(256) void gemm_kernel(const bf16_t* __restrict__ A,
                                                   const bf16_t* __restrict__ B,
                                                   void* __restrict__ C,
                                                   const float* __restrict__ aux,
                                                   int N, int K) {
    __shared__ __align__(16) bf16_t lds_a[128 * 32];
    __shared__ __align__(16) bf16_t lds_b[128 * 32];
    const int t = threadIdx.x;
    const int row0 = blockIdx.y * 128;
    const int col0 = blockIdx.x * 128;
    const bf16_t* Ap = A + (size_t)row0 * K;
    const bf16_t* Bp = B + (size_t)col0 * K;
    const int lane = t & 63, wave = t >> 6;
    const int wr = (wave >> 1) * 64, wc = (wave & 1) * 64;
    const int lrow = lane & 15, lk = (lane >> 4) * 8;

    f32x4 acc[4][4];
    f32x4 zero = {0.f, 0.f, 0.f, 0.f};
#pragma unroll
    for (int i = 0; i < 4; i++)
#pragma unroll
        for (int j = 0; j < 4; j++) acc[i][j] = zero;

    // staging assignment: thread t covers rows r0 and r0+64, k-chunk kc0 (8 bf16 = 16B)
    const int r0 = t >> 2;
    const int kc0 = (t & 3) * 8;
    const size_t aoff0 = (size_t)r0 * K + kc0;
    const size_t aoff1 = (size_t)(r0 + 64) * K + kc0;
    const int loff0 = r0 * 32 + kc0;
    const int loff1 = (r0 + 64) * 32 + kc0;

    for (int k0 = 0; k0 < K; k0 += 32) {
        u32x4 a0 = *(const u32x4*)(Ap + aoff0 + k0);
        u32x4 a1 = *(const u32x4*)(Ap + aoff1 + k0);
        u32x4 b0 = *(const u32x4*)(Bp + aoff0 + k0);
        u32x4 b1 = *(const u32x4*)(Bp + aoff1 + k0);
        *(u32x4*)(lds_a + loff0) = a0;
        *(u32x4*)(lds_a + loff1) = a1;
        *(u32x4*)(lds_b + loff0) = b0;
        *(u32x4*)(lds_b + loff1) = b1;
        __syncthreads();
        bf16x8 af[4], bfr[4];
#pragma unroll
        for (int mi = 0; mi < 4; mi++)
            af[mi] = *(const bf16x8*)(lds_a + (wr + mi * 16 + lrow) * 32 + lk);
#pragma unroll
        for (int ni = 0; ni < 4; ni++)
            bfr[ni] = *(const bf16x8*)(lds_b + (wc + ni * 16 + lrow) * 32 + lk);
#pragma unroll
        for (int mi = 0; mi < 4; mi++) {
#pragma unroll
            for (int ni = 0; ni < 4; ni++) {
                acc[mi][ni] = __builtin_amdgcn_mfma_f32_16x16x32_bf16(
                    af[mi], bfr[ni], acc[mi][ni], 0, 0, 0);
            }
        }
        __syncthreads();
    }

    // epilogue: C/D layout col = lane&15, row = (lane>>4)*4 + reg  [m89-verified]
#pragma unroll
    for (int mi = 0; mi < 4; mi++) {
        int rbase = row0 + wr + mi * 16 + (lane >> 4) * 4;
#pragma unroll
        for (int ni = 0; ni < 4; ni++) {
            int col = col0 + wc + ni * 16 + (lane & 15);
#pragma unroll
            for (int r = 0; r < 4; r++) {
                float v = acc[mi][ni][r];
                size_t idx = (size_t)(rbase + r) * N + col;
                if (EPI == 1) {
                    ((float*)C)[idx] = v + aux[idx];
                } else if (EPI == 2) {
                    ((bf16_t*)C)[idx] = (bf16_t)gelu_exact(v);
                } else if (EPI == 3) {
                    ((float*)C)[idx] += aux[(size_t)(rbase + r) * 4] * v;
                } else {
                    ((bf16_t*)C)[idx] = (bf16_t)v;
                }
            }
        }
    }
}

// ---------------- unpack 2 bf16 from a u32 ----------------
__device__ inline void bf2(unsigned u, float& a, float& b) {
    union { unsigned v; float f; } t0, t1;
    t0.v = u << 16;
    t1.v = u & 0xffff0000u;
    a = t0.f; b = t1.f;
}

// ---------------- causal flash attention (VALU), 4 lanes per query ----------------
// grid: (B*H*T/64) blocks of 256 thr; wave = 16 queries; lane = (query<<2)|d-quarter
__global__ __launch_bounds__(256) void attn_kernel(const bf16_t* __restrict__ Q,
                                                   const bf16_t* __restrict__ Km,
                                                   const bf16_t* __restrict__ Vm,
                                                   bf16_t* __restrict__ O) {
    const int qblk = blockIdx.x & 15;
    const int bh = blockIdx.x >> 4;
    const int h = bh & 7, b = bh >> 3;
    const int t = threadIdx.x, wave = t >> 6, lane = t & 63;
    const int qi = qblk * 64 + wave * 16 + (lane >> 2);
    const int dsub = (lane & 3) * 16;

    const bf16_t* qrow = Q + ((size_t)(b * 1024 + qi) * 512 + h * 64 + dsub);
    float q[16];
    {
        u32x4 a = ((const u32x4*)qrow)[0];
        u32x4 c = ((const u32x4*)qrow)[1];
        bf2(a.x, q[0], q[1]);  bf2(a.y, q[2], q[3]);
        bf2(a.z, q[4], q[5]);  bf2(a.w, q[6], q[7]);
        bf2(c.x, q[8], q[9]);  bf2(c.y, q[10], q[11]);
        bf2(c.z, q[12], q[13]); bf2(c.w, q[14], q[15]);
    }
    float o[16];
#pragma unroll
    for (int i = 0; i < 16; i++) o[i] = 0.f;
    float m = -1e30f, denom = 0.f;
    const int kend = qblk * 64 + wave * 16 + 15;
    const bf16_t* kbase = Km + ((size_t)b * 1024 * 512 + h * 64 + dsub);
    const bf16_t* vbase = Vm + ((size_t)b * 1024 * 512 + h * 64 + dsub);

    for (int key = 0; key <= kend; ++key) {
        const u32x4* kr = (const u32x4*)(kbase + (size_t)key * 512);
        const u32x4* vr = (const u32x4*)(vbase + (size_t)key * 512);
        u32x4 ka = kr[0], kc = kr[1], va = vr[0], vc = vr[1];
        float kk[16], vv[16];
        bf2(ka.x, kk[0], kk[1]);   bf2(ka.y, kk[2], kk[3]);
        bf2(ka.z, kk[4], kk[5]);   bf2(ka.w, kk[6], kk[7]);
        bf2(kc.x, kk[8], kk[9]);   bf2(kc.y, kk[10], kk[11]);
        bf2(kc.z, kk[12], kk[13]); bf2(kc.w, kk[14], kk[15]);
        bf2(va.x, vv[0], vv[1]);   bf2(va.y, vv[2], vv[3]);
        bf2(va.z, vv[4], vv[5]);   bf2(va.w, vv[6], vv[7]);
        bf2(vc.x, vv[8], vv[9]);   bf2(vc.y, vv[10], vv[11]);
        bf2(vc.z, vv[12], vv[13]); bf2(vc.w, vv[14], vv[15]);

        float s0 = 0.f, s1 = 0.f, s2 = 0.f, s3 = 0.f;
#pragma unroll
        for (int i = 0; i < 4; i++) {
            s0 = fmaf(q[i],      kk[i],      s0);
            s1 = fmaf(q[4 + i],  kk[4 + i],  s1);
            s2 = fmaf(q[8 + i],  kk[8 + i],  s2);
            s3 = fmaf(q[12 + i], kk[12 + i], s3);
        }
        float s = (s0 + s1) + (s2 + s3);
        s += __shfl_xor(s, 1);
        s += __shfl_xor(s, 2);
        s *= 0.125f;                       // 1/sqrt(64)
        if (key > qi) s = -1e30f;          // causal mask
        float mn = fmaxf(m, s);
        float co = __expf(m - mn);
        float p  = __expf(s - mn);
        denom = denom * co + p;
#pragma unroll
        for (int i = 0; i < 16; i++) o[i] = fmaf(p, vv[i], o[i] * co);
        m = mn;
    }
    float inv = 1.0f / denom;
    union { bf16_t b2[8]; u32x4 v; } w0, w1;
#pragma unroll
    for (int i = 0; i < 8; i++) w0.b2[i] = (bf16_t)(o[i] * inv);
#pragma unroll
    for (int i = 0; i < 8; i++) w1.b2[i] = (bf16_t)(o[8 + i] * inv);
    bf16_t* op = O + ((size_t)(b * 1024 + qi) * 512 + h * 64 + dsub);
    *((u32x4*)op) = w0.v;
    *((u32x4*)(op + 8)) = w1.v;
}

// ---------------- router: FULL f32 (rmsnorm + gate + softmax + top2) ----------------
// f32 path is required: top-k selection is discontinuous, bf16 logits flip experts.
__global__ __launch_bounds__(256) void router_kernel(const float* __restrict__ xr,
                                                     const float* __restrict__ w,
                                                     const float* __restrict__ gw,
                                                     float* __restrict__ out) {
    const int n = blockIdx.x * 256 + threadIdx.x;
    const float* row = xr + (size_t)n * 512;
    float ss = 0.f;
    for (int c = 0; c < 512; c += 4) {
        f32x4 v = *(const f32x4*)(row + c);
        ss += v.x * v.x + v.y * v.y + v.z * v.z + v.w * v.w;
    }
    float sc = rsqrtf(ss * (1.0f / 512.0f) + 1e-5f);
    float l0 = 0.f, l1 = 0.f, l2 = 0.f, l3 = 0.f;
    for (int c = 0; c < 512; c += 4) {
        f32x4 v = *(const f32x4*)(row + c);
        f32x4 wv = *(const f32x4*)(w + c);
        f32x4 xw;
        xw.x = v.x * wv.x; xw.y = v.y * wv.y; xw.z = v.z * wv.z; xw.w = v.w * wv.w;
        f32x4 g0 = *(const f32x4*)(gw + c);
        f32x4 g1 = *(const f32x4*)(gw + 512 + c);
        f32x4 g2 = *(const f32x4*)(gw + 1024 + c);
        f32x4 g3 = *(const f32x4*)(gw + 1536 + c);
        l0 += xw.x * g0.x + xw.y * g0.y + xw.z * g0.z + xw.w * g0.w;
        l1 += xw.x * g1.x + xw.y * g1.y + xw.z * g1.z + xw.w * g1.w;
        l2 += xw.x * g2.x + xw.y * g2.y + xw.z * g2.z + xw.w * g2.w;
        l3 += xw.x * g3.x + xw.y * g3.y + xw.z * g3.z + xw.w * g3.w;
    }
    l0 *= sc; l1 *= sc; l2 *= sc; l3 *= sc;
    float mx = fmaxf(fmaxf(l0, l1), fmaxf(l2, l3));
    float p[4];
    p[0] = expf(l0 - mx); p[1] = expf(l1 - mx);
    p[2] = expf(l2 - mx); p[3] = expf(l3 - mx);
    float s = (p[0] + p[1]) + (p[2] + p[3]);
    float is = 1.0f / s;
    p[0] *= is; p[1] *= is; p[2] *= is; p[3] *= is;
    int i0 = 0; float b0 = p[0];
#pragma unroll
    for (int e = 1; e < 4; e++) if (p[e] > b0) { b0 = p[e]; i0 = e; }
    int i1 = -1; float b1 = -1.f;
#pragma unroll
    for (int e = 0; e < 4; e++) {
        if (e == i0) continue;
        if (p[e] > b1) { b1 = p[e]; i1 = e; }
    }
    float inv2 = 1.0f / fmaxf(b0 + b1, 1e-6f);
    float o[4] = {0.f, 0.f, 0.f, 0.f};
    o[i0] = b0 * inv2;
    o[i1] = b1 * inv2;
    f32x4 ov; ov.x = o[0]; ov.y = o[1]; ov.z = o[2]; ov.w = o[3];
    *(f32x4*)(out + (size_t)n * 4) = ov;
}

extern "C" void kernel_launch(void* const* d_in, const int* in_sizes, int n_in,
                              void* d_out, int out_size, void* d_ws, size_t ws_size,
                              hipStream_t stream) {
    (void)in_sizes; (void)n_in; (void)out_size; (void)ws_size;
    const float* x   = (const float*)d_in[0];
    const float* ln1 = (const float*)d_in[1];
    const float* ln2 = (const float*)d_in[2];
    const float* wq  = (const float*)d_in[3];
    const float* wk  = (const float*)d_in[4];
    const float* wv  = (const float*)d_in[5];
    const float* wo  = (const float*)d_in[6];
    const float* gw  = (const float*)d_in[7];
    const float* wfc = (const float*)d_in[8];
    const float* wpj = (const float*)d_in[9];

    char* ws = (char*)d_ws;
    // ws layout (bytes):
    //   0..8MB    hb    bf16 [8192,512]   (h1 then h2)
    //   8..16MB   qb    bf16
    //   16..24MB  kb    bf16
    //   24..32MB  vb    bf16
    //   32..40MB  attb  bf16
    //   8..40MB   Hb    bf16 [8192,2048]  (overlaps q/k/v/att — those are dead by MoE phase)
    //   40..42MB  wq/wk/wv/wo bf16
    //   42..50MB  wfc bf16, 50..58MB wproj bf16
    bf16_t* hb   = (bf16_t*)(ws);
    bf16_t* qb   = (bf16_t*)(ws + 8 * WS_MB);
    bf16_t* kb   = (bf16_t*)(ws + 16 * WS_MB);
    bf16_t* vb   = (bf16_t*)(ws + 24 * WS_MB);
    bf16_t* attb = (bf16_t*)(ws + 32 * WS_MB);
    bf16_t* Hb   = (bf16_t*)(ws + 8 * WS_MB);
    bf16_t* wqb  = (bf16_t*)(ws + 40 * WS_MB);
    bf16_t* wkb  = (bf16_t*)(ws + 40 * WS_MB + 512 * 1024);
    bf16_t* wvb  = (bf16_t*)(ws + 41 * WS_MB);
    bf16_t* wob  = (bf16_t*)(ws + 41 * WS_MB + 512 * 1024);
    bf16_t* wfcb = (bf16_t*)(ws + 42 * WS_MB);
    bf16_t* wpjb = (bf16_t*)(ws + 50 * WS_MB);

    float* xout   = (float*)d_out;                 // [8192,512] final x
    float* router = xout + (size_t)8192 * 512;     // [8192,4] sparse router weights

    // weight conversion f32 -> bf16
    cvt_kernel<<<256, 256, 0, stream>>>(wq, wqb, 65536);
    cvt_kernel<<<256, 256, 0, stream>>>(wk, wkb, 65536);
    cvt_kernel<<<256, 256, 0, stream>>>(wv, wvb, 65536);
    cvt_kernel<<<256, 256, 0, stream>>>(wo, wob, 65536);
    cvt_kernel<<<4096, 256, 0, stream>>>(wfc, wfcb, 1048576);
    cvt_kernel<<<4096, 256, 0, stream>>>(wpj, wpjb, 1048576);

    dim3 g512(4, 64), g2048(16, 64);

    // h1 = rmsnorm(x) ; q,k,v = h1 @ w{q,k,v}^T
    rmsnorm_kernel<<<8192, 256, 0, stream>>>(x, ln1, hb);
    gemm_kernel<4><<<g512, 256, 0, stream>>>(hb, wqb, (void*)qb, nullptr, 512, 512);
    gemm_kernel<4><<<g512, 256, 0, stream>>>(hb, wkb, (void*)kb, nullptr, 512, 512);
    gemm_kernel<4><<<g512, 256, 0, stream>>>(hb, wvb, (void*)vb, nullptr, 512, 512);

    // causal attention
    attn_kernel<<<1024, 256, 0, stream>>>(qb, kb, vb, attb);

    // x_res = x + attn @ wo^T   (written to d_out)
    gemm_kernel<1><<<g512, 256, 0, stream>>>(attb, wob, (void*)xout, x, 512, 512);

    // h2 = rmsnorm(x_res) (bf16, for expert GEMMs); router in full f32
    rmsnorm_kernel<<<8192, 256, 0, stream>>>(xout, ln2, hb);
    router_kernel<<<32, 256, 0, stream>>>(xout, ln2, gw, router);

    // MoE (dense v1: all 4 experts, weighted accumulate; sparse_w zeros kill non-top2)
    for (int e = 0; e < 4; e++) {
        gemm_kernel<2><<<g2048, 256, 0, stream>>>(hb, wfcb + (size_t)e * 2048 * 512,
                                                  (void*)Hb, nullptr, 2048, 512);
        gemm_kernel<3><<<g512, 256, 0, stream>>>(Hb, wpjb + (size_t)e * 512 * 2048,
                                                 (void*)xout, router + e, 512, 2048);
    }
}

// Round 4
// 577.896 us; speedup vs baseline: 2.1277x; 2.1277x over previous
//
#include <hip/hip_runtime.h>
#include <math.h>

typedef __bf16 bf16_t;
typedef float    f32x2 __attribute__((ext_vector_type(2)));
typedef float    f32x4 __attribute__((ext_vector_type(4)));
typedef unsigned u32x2 __attribute__((ext_vector_type(2)));
typedef unsigned u32x4 __attribute__((ext_vector_type(4)));
typedef __bf16   bf16x8 __attribute__((ext_vector_type(8)));

#define WS_MB (size_t)(1u << 20)

// ---------------- f32 -> bf16 convert (4 elems / thread) ----------------
__global__ __launch_bounds__(256) void cvt_kernel(const float* __restrict__ in,
                                                  bf16_t* __restrict__ out, int n4) {
    int i = blockIdx.x * 256 + threadIdx.x;
    if (i >= n4) return;
    f32x4 v = ((const f32x4*)in)[i];
    union { bf16_t b[4]; u32x2 u; } p;
    p.b[0] = (bf16_t)v.x; p.b[1] = (bf16_t)v.y;
    p.b[2] = (bf16_t)v.z; p.b[3] = (bf16_t)v.w;
    ((u32x2*)out)[i] = p.u;
}

// ---------------- RMSNorm: f32 in -> bf16 out (one block per row, C=512) ----------------
__global__ __launch_bounds__(256) void rmsnorm_kernel(const float* __restrict__ x,
                                                      const float* __restrict__ w,
                                                      bf16_t* __restrict__ out) {
    int row = blockIdx.x;
    const float* xr = x + (size_t)row * 512;
    int t = threadIdx.x;
    f32x2 v = *(const f32x2*)(xr + t * 2);
    float ss = v.x * v.x + v.y * v.y;
#pragma unroll
    for (int o = 32; o > 0; o >>= 1) ss += __shfl_down(ss, o);
    __shared__ float red[4];
    if ((t & 63) == 0) red[t >> 6] = ss;
    __syncthreads();
    float tot = (red[0] + red[1]) + (red[2] + red[3]);
    float sc = rsqrtf(tot * (1.0f / 512.0f) + 1e-5f);
    f32x2 wv = *(const f32x2*)(w + t * 2);
    union { bf16_t b[2]; unsigned u; } p;
    p.b[0] = (bf16_t)(v.x * sc * wv.x);
    p.b[1] = (bf16_t)(v.y * sc * wv.y);
    *(unsigned*)(out + (size_t)row * 512 + t * 2) = p.u;
}

__device__ inline float gelu_exact(float v) {
    return 0.5f * v * (1.0f + erff(v * 0.70710678118654752f));
}

// ---------------- bf16 MFMA GEMM: C[n,o] = sum_c A[n,c]*B[o,c] ----------------
// 128x128 tile, BK=32, 4 waves (2x2), 4x4 16x16 frags per wave.
// EPI: 1 = f32 out = acc + aux[idx] (residual add)
//      2 = bf16 out = gelu(acc)
//      3 = f32 out += aux[row*4] * acc   (MoE weighted accumulate; aux pre-offset by expert)
//      4 = bf16 out = acc
template <int EPI>
__global__ __launch_bounds__(256) void gemm_kernel(const bf16_t* __restrict__ A,
                                                   const bf16_t* __restrict__ B,
                                                   void* __restrict__ C,
                                                   const float* __restrict__ aux,
                                                   int N, int K) {
    __shared__ __align__(16) bf16_t lds_a[128 * 32];
    __shared__ __align__(16) bf16_t lds_b[128 * 32];
    const int t = threadIdx.x;
    const int row0 = blockIdx.y * 128;
    const int col0 = blockIdx.x * 128;
    const bf16_t* Ap = A + (size_t)row0 * K;
    const bf16_t* Bp = B + (size_t)col0 * K;
    const int lane = t & 63, wave = t >> 6;
    const int wr = (wave >> 1) * 64, wc = (wave & 1) * 64;
    const int lrow = lane & 15, lk = (lane >> 4) * 8;

    f32x4 acc[4][4];
    f32x4 zero = {0.f, 0.f, 0.f, 0.f};
#pragma unroll
    for (int i = 0; i < 4; i++)
#pragma unroll
        for (int j = 0; j < 4; j++) acc[i][j] = zero;

    const int r0 = t >> 2;
    const int kc0 = (t & 3) * 8;
    const size_t aoff0 = (size_t)r0 * K + kc0;
    const size_t aoff1 = (size_t)(r0 + 64) * K + kc0;
    const int loff0 = r0 * 32 + kc0;
    const int loff1 = (r0 + 64) * 32 + kc0;

    for (int k0 = 0; k0 < K; k0 += 32) {
        u32x4 a0 = *(const u32x4*)(Ap + aoff0 + k0);
        u32x4 a1 = *(const u32x4*)(Ap + aoff1 + k0);
        u32x4 b0 = *(const u32x4*)(Bp + aoff0 + k0);
        u32x4 b1 = *(const u32x4*)(Bp + aoff1 + k0);
        *(u32x4*)(lds_a + loff0) = a0;
        *(u32x4*)(lds_a + loff1) = a1;
        *(u32x4*)(lds_b + loff0) = b0;
        *(u32x4*)(lds_b + loff1) = b1;
        __syncthreads();
        bf16x8 af[4], bfr[4];
#pragma unroll
        for (int mi = 0; mi < 4; mi++)
            af[mi] = *(const bf16x8*)(lds_a + (wr + mi * 16 + lrow) * 32 + lk);
#pragma unroll
        for (int ni = 0; ni < 4; ni++)
            bfr[ni] = *(const bf16x8*)(lds_b + (wc + ni * 16 + lrow) * 32 + lk);
#pragma unroll
        for (int mi = 0; mi < 4; mi++) {
#pragma unroll
            for (int ni = 0; ni < 4; ni++) {
                acc[mi][ni] = __builtin_amdgcn_mfma_f32_16x16x32_bf16(
                    af[mi], bfr[ni], acc[mi][ni], 0, 0, 0);
            }
        }
        __syncthreads();
    }

#pragma unroll
    for (int mi = 0; mi < 4; mi++) {
        int rbase = row0 + wr + mi * 16 + (lane >> 4) * 4;
#pragma unroll
        for (int ni = 0; ni < 4; ni++) {
            int col = col0 + wc + ni * 16 + (lane & 15);
#pragma unroll
            for (int r = 0; r < 4; r++) {
                float v = acc[mi][ni][r];
                size_t idx = (size_t)(rbase + r) * N + col;
                if (EPI == 1) {
                    ((float*)C)[idx] = v + aux[idx];
                } else if (EPI == 2) {
                    ((bf16_t*)C)[idx] = (bf16_t)gelu_exact(v);
                } else if (EPI == 3) {
                    ((float*)C)[idx] += aux[(size_t)(rbase + r) * 4] * v;
                } else {
                    ((bf16_t*)C)[idx] = (bf16_t)v;
                }
            }
        }
    }
}

// ---------------- MFMA causal flash attention ----------------
// Grid: 1024 blocks (qb longest-first), 256 thr = 4 waves, wave = 16 queries.
// S^T = mfma(K_perm, Q): lane owns query col q=lane&15; key-permuted tiles
// (perm(i)=8*(i>>2)+(i&3), tile tau adds 4) make S^T C/D regs land exactly in
// the 16x16x32 B-frag layout (k=(lane>>4)*8+j) -> PV needs NO cross-lane moves.
// V staged transposed in LDS as [db][kh][16 dq][32 k] (64B rows = the GEMM
// ds_read_b128 pattern that measured 0 bank conflicts in R2).
__global__ __launch_bounds__(256) void attn_kernel(const bf16_t* __restrict__ Q,
                                                   const bf16_t* __restrict__ Km,
                                                   const bf16_t* __restrict__ Vm,
                                                   bf16_t* __restrict__ O) {
    __shared__ __align__(16) bf16_t klds[2 * 64 * 32];   // [dhalf][key row][32 d]
    __shared__ __align__(16) bf16_t vlds[4 * 2 * 16 * 32]; // [db][kh][dq][k32]

    const int bx = blockIdx.x;
    const int qb = 15 - (bx >> 6);        // longest-first
    const int bh = bx & 63;
    const int b = bh >> 3, h = bh & 7;
    const int t = threadIdx.x;
    const int lane = t & 63, wave = t >> 6;
    const int g = lane >> 4, q15 = lane & 15;
    const int qbase = qb * 64 + wave * 16;
    const int qabs = qbase + q15;

    const size_t bh_off = (size_t)b * 1024 * 512 + h * 64;

    // Q B-frags (col=q=lane&15, k=d=(lane>>4)*8+j)
    const bf16_t* qp = Q + bh_off + (size_t)(qbase + q15) * 512 + g * 8;
    bf16x8 qf0 = *(const bf16x8*)(qp);
    bf16x8 qf1 = *(const bf16x8*)(qp + 32);

    f32x4 acc[4];
    f32x4 zero = {0.f, 0.f, 0.f, 0.f};
#pragma unroll
    for (int i = 0; i < 4; i++) acc[i] = zero;
    float m = -1e30f, denom = 0.f;

    // staging: K units (row=u>>3, chunk=u&7, coalesced); V units key-major
    // (row=u&63, chunk=u>>6) so transposed b16 LDS writes are ~2-way (free).
    const int kr1 = t >> 3, kc1 = t & 7;
    const int vr = t & 63, vc1 = t >> 6, vc2 = vc1 + 4;
    const int perm = ((q15 >> 2) * 8) + (q15 & 3);

    const int nkt = qb + 1;
    for (int kt = 0; kt < nkt; ++kt) {
        const size_t krow = bh_off + (size_t)(kt * 64) * 512;
        u32x4 ka  = *(const u32x4*)(Km + krow + (size_t)kr1 * 512 + kc1 * 8);
        u32x4 kb2 = *(const u32x4*)(Km + krow + (size_t)(kr1 + 32) * 512 + kc1 * 8);
        u32x4 va  = *(const u32x4*)(Vm + krow + (size_t)vr * 512 + vc1 * 8);
        u32x4 vb2 = *(const u32x4*)(Vm + krow + (size_t)vr * 512 + vc2 * 8);
        __syncthreads();   // previous tile fully consumed
        *(u32x4*)(klds + (kc1 >> 2) * 2048 + kr1 * 32 + (kc1 & 3) * 8) = ka;
        *(u32x4*)(klds + (kc1 >> 2) * 2048 + (kr1 + 32) * 32 + (kc1 & 3) * 8) = kb2;
        {
            union { u32x4 u; bf16_t e[8]; } tv;
            const int kh = vr >> 5, k32 = vr & 31;
            tv.u = va;
#pragma unroll
            for (int j = 0; j < 8; ++j) {
                int d = vc1 * 8 + j;
                vlds[(((d >> 4) * 2 + kh) * 16 + (d & 15)) * 32 + k32] = tv.e[j];
            }
            tv.u = vb2;
#pragma unroll
            for (int j = 0; j < 8; ++j) {
                int d = vc2 * 8 + j;
                vlds[(((d >> 4) * 2 + kh) * 16 + (d & 15)) * 32 + k32] = tv.e[j];
            }
        }
        __syncthreads();

        for (int s32 = 0; s32 < 2; ++s32) {
            const int KB = kt * 64 + s32 * 32;
            if (KB > qbase + 15) break;   // fully masked for this wave
            const int r0 = s32 * 32 + perm;
            // A-frags: K rows permuted so C/D key = KB + 8g + (4*tau + r)
            bf16x8 k00 = *(const bf16x8*)(klds + r0 * 32 + g * 8);
            bf16x8 k01 = *(const bf16x8*)(klds + 2048 + r0 * 32 + g * 8);
            bf16x8 k10 = *(const bf16x8*)(klds + (r0 + 4) * 32 + g * 8);
            bf16x8 k11 = *(const bf16x8*)(klds + 2048 + (r0 + 4) * 32 + g * 8);
            f32x4 s0 = zero, s1 = zero;
            s0 = __builtin_amdgcn_mfma_f32_16x16x32_bf16(k00, qf0, s0, 0, 0, 0);
            s0 = __builtin_amdgcn_mfma_f32_16x16x32_bf16(k01, qf1, s0, 0, 0, 0);
            s1 = __builtin_amdgcn_mfma_f32_16x16x32_bf16(k10, qf0, s1, 0, 0, 0);
            s1 = __builtin_amdgcn_mfma_f32_16x16x32_bf16(k11, qf1, s1, 0, 0, 0);

            // mask + scale: key_j = KB + 8g + j  (j = 4*tau + r)
            const int kbg = KB + 8 * g;
            float sv[8];
#pragma unroll
            for (int r = 0; r < 4; ++r) {
                sv[r]     = (kbg + r     <= qabs) ? s0[r] * 0.125f : -1e30f;
                sv[4 + r] = (kbg + 4 + r <= qabs) ? s1[r] * 0.125f : -1e30f;
            }
            float tm = sv[0];
#pragma unroll
            for (int j = 1; j < 8; ++j) tm = fmaxf(tm, sv[j]);
            tm = fmaxf(tm, __shfl_xor(tm, 16));
            tm = fmaxf(tm, __shfl_xor(tm, 32));
            const float mn = fmaxf(m, tm);
            const float co = __expf(m - mn);
            float p[8];
            float ts = 0.f;
#pragma unroll
            for (int j = 0; j < 8; ++j) { p[j] = __expf(sv[j] - mn); ts += p[j]; }
            ts += __shfl_xor(ts, 16);
            ts += __shfl_xor(ts, 32);
            denom = denom * co + ts;
            m = mn;
            union { bf16_t e[8]; bf16x8 v; } pp;
#pragma unroll
            for (int j = 0; j < 8; ++j) pp.e[j] = (bf16_t)p[j];

#pragma unroll
            for (int db = 0; db < 4; ++db) {
                acc[db] *= co;
                bf16x8 vf = *(const bf16x8*)(vlds + ((db * 2 + s32) * 16 + q15) * 32 + g * 8);
                acc[db] = __builtin_amdgcn_mfma_f32_16x16x32_bf16(vf, pp.v, acc[db], 0, 0, 0);
            }
        }
    }

    const float inv = 1.0f / denom;
    bf16_t* op = O + bh_off + (size_t)qabs * 512;
#pragma unroll
    for (int db = 0; db < 4; ++db) {
        union { bf16_t e[4]; u32x2 u; } w;
#pragma unroll
        for (int r = 0; r < 4; ++r) w.e[r] = (bf16_t)(acc[db][r] * inv);
        *(u32x2*)(op + db * 16 + g * 4) = w.u;   // d = db*16 + 4g + r
    }
}

// ---------------- router: FULL f32 (rmsnorm + gate + softmax + top2) ----------------
__global__ __launch_bounds__(256) void router_kernel(const float* __restrict__ xr,
                                                     const float* __restrict__ w,
                                                     const float* __restrict__ gw,
                                                     float* __restrict__ out) {
    const int n = blockIdx.x * 256 + threadIdx.x;
    const float* row = xr + (size_t)n * 512;
    float ss = 0.f;
    for (int c = 0; c < 512; c += 4) {
        f32x4 v = *(const f32x4*)(row + c);
        ss += v.x * v.x + v.y * v.y + v.z * v.z + v.w * v.w;
    }
    float sc = rsqrtf(ss * (1.0f / 512.0f) + 1e-5f);
    float l0 = 0.f, l1 = 0.f, l2 = 0.f, l3 = 0.f;
    for (int c = 0; c < 512; c += 4) {
        f32x4 v = *(const f32x4*)(row + c);
        f32x4 wv = *(const f32x4*)(w + c);
        f32x4 xw;
        xw.x = v.x * wv.x; xw.y = v.y * wv.y; xw.z = v.z * wv.z; xw.w = v.w * wv.w;
        f32x4 g0 = *(const f32x4*)(gw + c);
        f32x4 g1 = *(const f32x4*)(gw + 512 + c);
        f32x4 g2 = *(const f32x4*)(gw + 1024 + c);
        f32x4 g3 = *(const f32x4*)(gw + 1536 + c);
        l0 += xw.x * g0.x + xw.y * g0.y + xw.z * g0.z + xw.w * g0.w;
        l1 += xw.x * g1.x + xw.y * g1.y + xw.z * g1.z + xw.w * g1.w;
        l2 += xw.x * g2.x + xw.y * g2.y + xw.z * g2.z + xw.w * g2.w;
        l3 += xw.x * g3.x + xw.y * g3.y + xw.z * g3.z + xw.w * g3.w;
    }
    l0 *= sc; l1 *= sc; l2 *= sc; l3 *= sc;
    float mx = fmaxf(fmaxf(l0, l1), fmaxf(l2, l3));
    float p[4];
    p[0] = expf(l0 - mx); p[1] = expf(l1 - mx);
    p[2] = expf(l2 - mx); p[3] = expf(l3 - mx);
    float s = (p[0] + p[1]) + (p[2] + p[3]);
    float is = 1.0f / s;
    p[0] *= is; p[1] *= is; p[2] *= is; p[3] *= is;
    int i0 = 0; float b0 = p[0];
#pragma unroll
    for (int e = 1; e < 4; e++) if (p[e] > b0) { b0 = p[e]; i0 = e; }
    int i1 = -1; float b1 = -1.f;
#pragma unroll
    for (int e = 0; e < 4; e++) {
        if (e == i0) continue;
        if (p[e] > b1) { b1 = p[e]; i1 = e; }
    }
    float inv2 = 1.0f / fmaxf(b0 + b1, 1e-6f);
    float o[4] = {0.f, 0.f, 0.f, 0.f};
    o[i0] = b0 * inv2;
    o[i1] = b1 * inv2;
    f32x4 ov; ov.x = o[0]; ov.y = o[1]; ov.z = o[2]; ov.w = o[3];
    *(f32x4*)(out + (size_t)n * 4) = ov;
}

extern "C" void kernel_launch(void* const* d_in, const int* in_sizes, int n_in,
                              void* d_out, int out_size, void* d_ws, size_t ws_size,
                              hipStream_t stream) {
    (void)in_sizes; (void)n_in; (void)out_size; (void)ws_size;
    const float* x   = (const float*)d_in[0];
    const float* ln1 = (const float*)d_in[1];
    const float* ln2 = (const float*)d_in[2];
    const float* wq  = (const float*)d_in[3];
    const float* wk  = (const float*)d_in[4];
    const float* wv  = (const float*)d_in[5];
    const float* wo  = (const float*)d_in[6];
    const float* gw  = (const float*)d_in[7];
    const float* wfc = (const float*)d_in[8];
    const float* wpj = (const float*)d_in[9];

    char* ws = (char*)d_ws;
    bf16_t* hb   = (bf16_t*)(ws);
    bf16_t* qb   = (bf16_t*)(ws + 8 * WS_MB);
    bf16_t* kb   = (bf16_t*)(ws + 16 * WS_MB);
    bf16_t* vb   = (bf16_t*)(ws + 24 * WS_MB);
    bf16_t* attb = (bf16_t*)(ws + 32 * WS_MB);
    bf16_t* Hb   = (bf16_t*)(ws + 8 * WS_MB);   // overlaps q/k/v/att (dead by MoE)
    bf16_t* wqb  = (bf16_t*)(ws + 40 * WS_MB);
    bf16_t* wkb  = (bf16_t*)(ws + 40 * WS_MB + 512 * 1024);
    bf16_t* wvb  = (bf16_t*)(ws + 41 * WS_MB);
    bf16_t* wob  = (bf16_t*)(ws + 41 * WS_MB + 512 * 1024);
    bf16_t* wfcb = (bf16_t*)(ws + 42 * WS_MB);
    bf16_t* wpjb = (bf16_t*)(ws + 50 * WS_MB);

    float* xout   = (float*)d_out;
    float* router = xout + (size_t)8192 * 512;

    cvt_kernel<<<256, 256, 0, stream>>>(wq, wqb, 65536);
    cvt_kernel<<<256, 256, 0, stream>>>(wk, wkb, 65536);
    cvt_kernel<<<256, 256, 0, stream>>>(wv, wvb, 65536);
    cvt_kernel<<<256, 256, 0, stream>>>(wo, wob, 65536);
    cvt_kernel<<<4096, 256, 0, stream>>>(wfc, wfcb, 1048576);
    cvt_kernel<<<4096, 256, 0, stream>>>(wpj, wpjb, 1048576);

    dim3 g512(4, 64), g2048(16, 64);

    rmsnorm_kernel<<<8192, 256, 0, stream>>>(x, ln1, hb);
    gemm_kernel<4><<<g512, 256, 0, stream>>>(hb, wqb, (void*)qb, nullptr, 512, 512);
    gemm_kernel<4><<<g512, 256, 0, stream>>>(hb, wkb, (void*)kb, nullptr, 512, 512);
    gemm_kernel<4><<<g512, 256, 0, stream>>>(hb, wvb, (void*)vb, nullptr, 512, 512);

    attn_kernel<<<1024, 256, 0, stream>>>(qb, kb, vb, attb);

    gemm_kernel<1><<<g512, 256, 0, stream>>>(attb, wob, (void*)xout, x, 512, 512);

    rmsnorm_kernel<<<8192, 256, 0, stream>>>(xout, ln2, hb);
    router_kernel<<<32, 256, 0, stream>>>(xout, ln2, gw, router);

    for (int e = 0; e < 4; e++) {
        gemm_kernel<2><<<g2048, 256, 0, stream>>>(hb, wfcb + (size_t)e * 2048 * 512,
                                                  (void*)Hb, nullptr, 2048, 512);
        gemm_kernel<3><<<g512, 256, 0, stream>>>(Hb, wpjb + (size_t)e * 512 * 2048,
                                                 (void*)xout, router + e, 512, 2048);
    }
}

// Round 5
// 535.767 us; speedup vs baseline: 2.2950x; 1.0786x over previous
//
#include <hip/hip_runtime.h>
#include <math.h>

typedef __bf16 bf16_t;
typedef float    f32x2 __attribute__((ext_vector_type(2)));
typedef float    f32x4 __attribute__((ext_vector_type(4)));
typedef unsigned u32x2 __attribute__((ext_vector_type(2)));
typedef unsigned u32x4 __attribute__((ext_vector_type(4)));
typedef __bf16   bf16x8 __attribute__((ext_vector_type(8)));

#define WS_MB (size_t)(1u << 20)

// async global->LDS, 16B per lane. LDS dest is WAVE-UNIFORM base (HW adds lane*16);
// global src is per-lane. [m97 structure]
__device__ __forceinline__ void gl16(const bf16_t* g, bf16_t* l) {
    void* gnc = const_cast<void*>((const void*)g);
    __builtin_amdgcn_global_load_lds((__attribute__((address_space(1))) void*)gnc,
                                     (__attribute__((address_space(3))) void*)l,
                                     16, 0, 0);
}

// ---------------- f32 -> bf16 convert (4 elems / thread) ----------------
__global__ __launch_bounds__(256) void cvt_kernel(const float* __restrict__ in,
                                                  bf16_t* __restrict__ out, int n4) {
    int i = blockIdx.x * 256 + threadIdx.x;
    if (i >= n4) return;
    f32x4 v = ((const f32x4*)in)[i];
    union { bf16_t b[4]; u32x2 u; } p;
    p.b[0] = (bf16_t)v.x; p.b[1] = (bf16_t)v.y;
    p.b[2] = (bf16_t)v.z; p.b[3] = (bf16_t)v.w;
    ((u32x2*)out)[i] = p.u;
}

// ---------------- RMSNorm: f32 in -> bf16 out ----------------
__global__ __launch_bounds__(256) void rmsnorm_kernel(const float* __restrict__ x,
                                                      const float* __restrict__ w,
                                                      bf16_t* __restrict__ out) {
    int row = blockIdx.x;
    const float* xr = x + (size_t)row * 512;
    int t = threadIdx.x;
    f32x2 v = *(const f32x2*)(xr + t * 2);
    float ss = v.x * v.x + v.y * v.y;
#pragma unroll
    for (int o = 32; o > 0; o >>= 1) ss += __shfl_down(ss, o);
    __shared__ float red[4];
    if ((t & 63) == 0) red[t >> 6] = ss;
    __syncthreads();
    float tot = (red[0] + red[1]) + (red[2] + red[3]);
    float sc = rsqrtf(tot * (1.0f / 512.0f) + 1e-5f);
    f32x2 wv = *(const f32x2*)(w + t * 2);
    union { bf16_t b[2]; unsigned u; } p;
    p.b[0] = (bf16_t)(v.x * sc * wv.x);
    p.b[1] = (bf16_t)(v.y * sc * wv.y);
    *(unsigned*)(out + (size_t)row * 512 + t * 2) = p.u;
}

__device__ inline float gelu_exact(float v) {
    return 0.5f * v * (1.0f + erff(v * 0.70710678118654752f));
}

// ---------------- bf16 MFMA GEMM, m97 structure ----------------
// C[n,o] = sum_c A[n,c]*B[o,c]. 128x128 tile, BK=64, 4 waves (2x2), 4x4 frags.
// Staging: global_load_lds dwordx4, linear LDS [128][64] bf16 (128B rows).
// Known 16-way ds_read conflict (m97 layout) — hidden behind 2-phase barrier drain.
// EPI: 1 = f32 out = acc + aux[idx]; 2 = bf16 out = gelu(acc);
//      3 = f32 out += aux[row*4]*acc; 4 = bf16 out = acc
template <int EPI>
__global__ __launch_bounds__(256) void gemm_kernel(const bf16_t* __restrict__ A,
                                                   const bf16_t* __restrict__ B,
                                                   void* __restrict__ C,
                                                   const float* __restrict__ aux,
                                                   int N, int K) {
    __shared__ __align__(16) bf16_t lds_a[128 * 64];
    __shared__ __align__(16) bf16_t lds_b[128 * 64];
    const int t = threadIdx.x;
    const int row0 = blockIdx.y * 128;
    const int col0 = blockIdx.x * 128;
    const bf16_t* Ap = A + (size_t)row0 * K;
    const bf16_t* Bp = B + (size_t)col0 * K;
    const int lane = t & 63, wave = t >> 6;
    const int wr = (wave >> 1) * 64, wc = (wave & 1) * 64;
    const int lrow = lane & 15, lk = (lane >> 4) * 8;

    // per-lane staging source: 8 rows x 128B per gl16 call
    const int srow = lane >> 3;          // 0..7
    const int scol = (lane & 7) * 8;     // bf16 col within BK=64

    f32x4 acc[4][4];
    f32x4 zero = {0.f, 0.f, 0.f, 0.f};
#pragma unroll
    for (int i = 0; i < 4; i++)
#pragma unroll
        for (int j = 0; j < 4; j++) acc[i][j] = zero;

    for (int k0 = 0; k0 < K; k0 += 64) {
        __syncthreads();   // previous tile's reads complete before overwrite
#pragma unroll
        for (int c = 0; c < 4; ++c) {
            const int rbase = wave * 32 + c * 8;       // wave-uniform
            gl16(Ap + (size_t)(rbase + srow) * K + k0 + scol, lds_a + rbase * 64);
            gl16(Bp + (size_t)(rbase + srow) * K + k0 + scol, lds_b + rbase * 64);
        }
        __syncthreads();   // compiler drains vmcnt(0) here: loads landed
#pragma unroll
        for (int kk = 0; kk < 2; ++kk) {
            bf16x8 af[4], bfr[4];
#pragma unroll
            for (int mi = 0; mi < 4; mi++)
                af[mi] = *(const bf16x8*)(lds_a + (wr + mi * 16 + lrow) * 64 + kk * 32 + lk);
#pragma unroll
            for (int ni = 0; ni < 4; ni++)
                bfr[ni] = *(const bf16x8*)(lds_b + (wc + ni * 16 + lrow) * 64 + kk * 32 + lk);
#pragma unroll
            for (int mi = 0; mi < 4; mi++) {
#pragma unroll
                for (int ni = 0; ni < 4; ni++) {
                    acc[mi][ni] = __builtin_amdgcn_mfma_f32_16x16x32_bf16(
                        af[mi], bfr[ni], acc[mi][ni], 0, 0, 0);
                }
            }
        }
    }

    // epilogue: C/D layout col = lane&15, row = (lane>>4)*4 + reg  [m89-verified]
#pragma unroll
    for (int mi = 0; mi < 4; mi++) {
        int rbase = row0 + wr + mi * 16 + (lane >> 4) * 4;
#pragma unroll
        for (int ni = 0; ni < 4; ni++) {
            int col = col0 + wc + ni * 16 + (lane & 15);
#pragma unroll
            for (int r = 0; r < 4; r++) {
                float v = acc[mi][ni][r];
                size_t idx = (size_t)(rbase + r) * N + col;
                if (EPI == 1) {
                    ((float*)C)[idx] = v + aux[idx];
                } else if (EPI == 2) {
                    ((bf16_t*)C)[idx] = (bf16_t)gelu_exact(v);
                } else if (EPI == 3) {
                    ((float*)C)[idx] += aux[(size_t)(rbase + r) * 4] * v;
                } else {
                    ((bf16_t*)C)[idx] = (bf16_t)v;
                }
            }
        }
    }
}

// ---------------- MFMA causal flash attention (packed QKV, row stride 1536) ----------------
// Grid: 1024 blocks (qb longest-first), 4 waves, wave = 16 queries.
// S^T = mfma(K_perm, Q); key-permuted tiles put S^T C/D regs exactly in the
// 16x16x32 B-frag layout -> PV needs no cross-lane moves. V transposed in LDS.
__global__ __launch_bounds__(256) void attn_kernel(const bf16_t* __restrict__ QKV,
                                                   bf16_t* __restrict__ O) {
    __shared__ __align__(16) bf16_t klds[2 * 64 * 32];     // [dhalf][key row][32 d]
    __shared__ __align__(16) bf16_t vlds[4 * 2 * 16 * 32]; // [db][kh][dq][k32]

    const int bx = blockIdx.x;
    const int qb = 15 - (bx >> 6);        // longest-first
    const int bh = bx & 63;
    const int b = bh >> 3, h = bh & 7;
    const int t = threadIdx.x;
    const int lane = t & 63, wave = t >> 6;
    const int g = lane >> 4, q15 = lane & 15;
    const int qbase = qb * 64 + wave * 16;
    const int qabs = qbase + q15;

    const bf16_t* Qb = QKV + (size_t)b * 1024 * 1536 + h * 64;        // q at +0
    const bf16_t* Kb = Qb + 512;                                       // k at +512
    const bf16_t* Vb = Qb + 1024;                                      // v at +1024

    const bf16_t* qp = Qb + (size_t)qabs * 1536 + g * 8;
    bf16x8 qf0 = *(const bf16x8*)(qp);
    bf16x8 qf1 = *(const bf16x8*)(qp + 32);

    f32x4 acc[4];
    f32x4 zero = {0.f, 0.f, 0.f, 0.f};
#pragma unroll
    for (int i = 0; i < 4; i++) acc[i] = zero;
    float m = -1e30f, denom = 0.f;

    const int kr1 = t >> 3, kc1 = t & 7;
    const int vr = t & 63, vc1 = t >> 6, vc2 = vc1 + 4;
    const int perm = ((q15 >> 2) * 8) + (q15 & 3);

    const int nkt = qb + 1;
    for (int kt = 0; kt < nkt; ++kt) {
        u32x4 ka  = *(const u32x4*)(Kb + (size_t)(kt * 64 + kr1) * 1536 + kc1 * 8);
        u32x4 kb2 = *(const u32x4*)(Kb + (size_t)(kt * 64 + kr1 + 32) * 1536 + kc1 * 8);
        u32x4 va  = *(const u32x4*)(Vb + (size_t)(kt * 64 + vr) * 1536 + vc1 * 8);
        u32x4 vb2 = *(const u32x4*)(Vb + (size_t)(kt * 64 + vr) * 1536 + vc2 * 8);
        __syncthreads();
        *(u32x4*)(klds + (kc1 >> 2) * 2048 + kr1 * 32 + (kc1 & 3) * 8) = ka;
        *(u32x4*)(klds + (kc1 >> 2) * 2048 + (kr1 + 32) * 32 + (kc1 & 3) * 8) = kb2;
        {
            union { u32x4 u; bf16_t e[8]; } tv;
            const int kh = vr >> 5, k32 = vr & 31;
            tv.u = va;
#pragma unroll
            for (int j = 0; j < 8; ++j) {
                int d = vc1 * 8 + j;
                vlds[(((d >> 4) * 2 + kh) * 16 + (d & 15)) * 32 + k32] = tv.e[j];
            }
            tv.u = vb2;
#pragma unroll
            for (int j = 0; j < 8; ++j) {
                int d = vc2 * 8 + j;
                vlds[(((d >> 4) * 2 + kh) * 16 + (d & 15)) * 32 + k32] = tv.e[j];
            }
        }
        __syncthreads();

        for (int s32 = 0; s32 < 2; ++s32) {
            const int KB = kt * 64 + s32 * 32;
            if (KB > qbase + 15) break;
            const int r0 = s32 * 32 + perm;
            bf16x8 k00 = *(const bf16x8*)(klds + r0 * 32 + g * 8);
            bf16x8 k01 = *(const bf16x8*)(klds + 2048 + r0 * 32 + g * 8);
            bf16x8 k10 = *(const bf16x8*)(klds + (r0 + 4) * 32 + g * 8);
            bf16x8 k11 = *(const bf16x8*)(klds + 2048 + (r0 + 4) * 32 + g * 8);
            f32x4 s0 = zero, s1 = zero;
            s0 = __builtin_amdgcn_mfma_f32_16x16x32_bf16(k00, qf0, s0, 0, 0, 0);
            s0 = __builtin_amdgcn_mfma_f32_16x16x32_bf16(k01, qf1, s0, 0, 0, 0);
            s1 = __builtin_amdgcn_mfma_f32_16x16x32_bf16(k10, qf0, s1, 0, 0, 0);
            s1 = __builtin_amdgcn_mfma_f32_16x16x32_bf16(k11, qf1, s1, 0, 0, 0);

            const int kbg = KB + 8 * g;
            float sv[8];
#pragma unroll
            for (int r = 0; r < 4; ++r) {
                sv[r]     = (kbg + r     <= qabs) ? s0[r] * 0.125f : -1e30f;
                sv[4 + r] = (kbg + 4 + r <= qabs) ? s1[r] * 0.125f : -1e30f;
            }
            float tm = sv[0];
#pragma unroll
            for (int j = 1; j < 8; ++j) tm = fmaxf(tm, sv[j]);
            tm = fmaxf(tm, __shfl_xor(tm, 16));
            tm = fmaxf(tm, __shfl_xor(tm, 32));
            const float mn = fmaxf(m, tm);
            const float co = __expf(m - mn);
            float p[8];
            float ts = 0.f;
#pragma unroll
            for (int j = 0; j < 8; ++j) { p[j] = __expf(sv[j] - mn); ts += p[j]; }
            ts += __shfl_xor(ts, 16);
            ts += __shfl_xor(ts, 32);
            denom = denom * co + ts;
            m = mn;
            union { bf16_t e[8]; bf16x8 v; } pp;
#pragma unroll
            for (int j = 0; j < 8; ++j) pp.e[j] = (bf16_t)p[j];

#pragma unroll
            for (int db = 0; db < 4; ++db) {
                acc[db] *= co;
                bf16x8 vf = *(const bf16x8*)(vlds + ((db * 2 + s32) * 16 + q15) * 32 + g * 8);
                acc[db] = __builtin_amdgcn_mfma_f32_16x16x32_bf16(vf, pp.v, acc[db], 0, 0, 0);
            }
        }
    }

    const float inv = 1.0f / denom;
    bf16_t* op = O + (size_t)b * 1024 * 512 + h * 64 + (size_t)qabs * 512;
#pragma unroll
    for (int db = 0; db < 4; ++db) {
        union { bf16_t e[4]; u32x2 u; } w;
#pragma unroll
        for (int r = 0; r < 4; ++r) w.e[r] = (bf16_t)(acc[db][r] * inv);
        *(u32x2*)(op + db * 16 + g * 4) = w.u;
    }
}

// ---------------- router: FULL f32 (top-k is discontinuous; no bf16 here) ----------------
__global__ __launch_bounds__(256) void router_kernel(const float* __restrict__ xr,
                                                     const float* __restrict__ w,
                                                     const float* __restrict__ gw,
                                                     float* __restrict__ out) {
    const int n = blockIdx.x * 256 + threadIdx.x;
    const float* row = xr + (size_t)n * 512;
    float ss = 0.f;
    for (int c = 0; c < 512; c += 4) {
        f32x4 v = *(const f32x4*)(row + c);
        ss += v.x * v.x + v.y * v.y + v.z * v.z + v.w * v.w;
    }
    float sc = rsqrtf(ss * (1.0f / 512.0f) + 1e-5f);
    float l0 = 0.f, l1 = 0.f, l2 = 0.f, l3 = 0.f;
    for (int c = 0; c < 512; c += 4) {
        f32x4 v = *(const f32x4*)(row + c);
        f32x4 wv = *(const f32x4*)(w + c);
        f32x4 xw;
        xw.x = v.x * wv.x; xw.y = v.y * wv.y; xw.z = v.z * wv.z; xw.w = v.w * wv.w;
        f32x4 g0 = *(const f32x4*)(gw + c);
        f32x4 g1 = *(const f32x4*)(gw + 512 + c);
        f32x4 g2 = *(const f32x4*)(gw + 1024 + c);
        f32x4 g3 = *(const f32x4*)(gw + 1536 + c);
        l0 += xw.x * g0.x + xw.y * g0.y + xw.z * g0.z + xw.w * g0.w;
        l1 += xw.x * g1.x + xw.y * g1.y + xw.z * g1.z + xw.w * g1.w;
        l2 += xw.x * g2.x + xw.y * g2.y + xw.z * g2.z + xw.w * g2.w;
        l3 += xw.x * g3.x + xw.y * g3.y + xw.z * g3.z + xw.w * g3.w;
    }
    l0 *= sc; l1 *= sc; l2 *= sc; l3 *= sc;
    float mx = fmaxf(fmaxf(l0, l1), fmaxf(l2, l3));
    float p[4];
    p[0] = expf(l0 - mx); p[1] = expf(l1 - mx);
    p[2] = expf(l2 - mx); p[3] = expf(l3 - mx);
    float s = (p[0] + p[1]) + (p[2] + p[3]);
    float is = 1.0f / s;
    p[0] *= is; p[1] *= is; p[2] *= is; p[3] *= is;
    int i0 = 0; float b0 = p[0];
#pragma unroll
    for (int e = 1; e < 4; e++) if (p[e] > b0) { b0 = p[e]; i0 = e; }
    int i1 = -1; float b1 = -1.f;
#pragma unroll
    for (int e = 0; e < 4; e++) {
        if (e == i0) continue;
        if (p[e] > b1) { b1 = p[e]; i1 = e; }
    }
    float inv2 = 1.0f / fmaxf(b0 + b1, 1e-6f);
    float o[4] = {0.f, 0.f, 0.f, 0.f};
    o[i0] = b0 * inv2;
    o[i1] = b1 * inv2;
    f32x4 ov; ov.x = o[0]; ov.y = o[1]; ov.z = o[2]; ov.w = o[3];
    *(f32x4*)(out + (size_t)n * 4) = ov;
}

extern "C" void kernel_launch(void* const* d_in, const int* in_sizes, int n_in,
                              void* d_out, int out_size, void* d_ws, size_t ws_size,
                              hipStream_t stream) {
    (void)in_sizes; (void)n_in; (void)out_size; (void)ws_size;
    const float* x   = (const float*)d_in[0];
    const float* ln1 = (const float*)d_in[1];
    const float* ln2 = (const float*)d_in[2];
    const float* wq  = (const float*)d_in[3];
    const float* wk  = (const float*)d_in[4];
    const float* wv  = (const float*)d_in[5];
    const float* wo  = (const float*)d_in[6];
    const float* gw  = (const float*)d_in[7];
    const float* wfc = (const float*)d_in[8];
    const float* wpj = (const float*)d_in[9];

    char* ws = (char*)d_ws;
    // ws layout: hb 0..8MB | qkvb [8192x1536] 8..32MB | attb 32..40MB
    //            Hb [8192x2048] 8..40MB (overlaps qkv/att, dead by MoE)
    //            wqkvb 40..41.5 | wob 41.5..42 | wfcb 42..50 | wpjb 50..58
    bf16_t* hb    = (bf16_t*)(ws);
    bf16_t* qkvb  = (bf16_t*)(ws + 8 * WS_MB);
    bf16_t* attb  = (bf16_t*)(ws + 32 * WS_MB);
    bf16_t* Hb    = (bf16_t*)(ws + 8 * WS_MB);
    bf16_t* wqkvb = (bf16_t*)(ws + 40 * WS_MB);
    bf16_t* wob   = (bf16_t*)(ws + 40 * WS_MB + 1536 * 1024);
    bf16_t* wfcb  = (bf16_t*)(ws + 42 * WS_MB);
    bf16_t* wpjb  = (bf16_t*)(ws + 50 * WS_MB);

    float* xout   = (float*)d_out;
    float* router = xout + (size_t)8192 * 512;

    cvt_kernel<<<256, 256, 0, stream>>>(wq, wqkvb, 65536);
    cvt_kernel<<<256, 256, 0, stream>>>(wk, wqkvb + 512 * 512, 65536);
    cvt_kernel<<<256, 256, 0, stream>>>(wv, wqkvb + 1024 * 512, 65536);
    cvt_kernel<<<256, 256, 0, stream>>>(wo, wob, 65536);
    cvt_kernel<<<4096, 256, 0, stream>>>(wfc, wfcb, 1048576);
    cvt_kernel<<<4096, 256, 0, stream>>>(wpj, wpjb, 1048576);

    // h1 = rmsnorm(x); qkv = h1 @ [wq;wk;wv]^T  (one GEMM, N=1536)
    rmsnorm_kernel<<<8192, 256, 0, stream>>>(x, ln1, hb);
    gemm_kernel<4><<<dim3(12, 64), 256, 0, stream>>>(hb, wqkvb, (void*)qkvb, nullptr, 1536, 512);

    attn_kernel<<<1024, 256, 0, stream>>>(qkvb, attb);

    // x_res = x + attn @ wo^T  -> d_out
    gemm_kernel<1><<<dim3(4, 64), 256, 0, stream>>>(attb, wob, (void*)xout, x, 512, 512);

    rmsnorm_kernel<<<8192, 256, 0, stream>>>(xout, ln2, hb);
    router_kernel<<<32, 256, 0, stream>>>(xout, ln2, gw, router);

    // MoE dense (all 4 experts; router zeros kill non-top2)
    for (int e = 0; e < 4; e++) {
        gemm_kernel<2><<<dim3(16, 64), 256, 0, stream>>>(hb, wfcb + (size_t)e * 2048 * 512,
                                                         (void*)Hb, nullptr, 2048, 512);
        gemm_kernel<3><<<dim3(4, 64), 256, 0, stream>>>(Hb, wpjb + (size_t)e * 512 * 2048,
                                                        (void*)xout, router + e, 512, 2048);
    }
}